// Round 2
// baseline (654.476 us; speedup 1.0000x reference)
//
#include <hip/hip_runtime.h>
#include <hip/hip_bf16.h>

typedef unsigned short u16;
typedef unsigned int u32;
typedef __attribute__((ext_vector_type(8))) short short8;   // 8 bf16 (4 VGPRs) MFMA A/B frag
typedef __attribute__((ext_vector_type(4))) float f32x4;    // MFMA C/D frag

__device__ __forceinline__ float bf2f(u16 u) {
    union { u32 i; float f; } v; v.i = ((u32)u) << 16; return v.f;
}
__device__ __forceinline__ u16 f2bf(float f) {
    union { float f; u32 i; } v; v.f = f;
    u32 r = v.i + 0x7fffu + ((v.i >> 16) & 1u);   // RNE
    return (u16)(r >> 16);
}
__device__ __forceinline__ float sigm(float x) {
    return __builtin_amdgcn_rcpf(1.0f + __expf(-x));
}
__device__ __forceinline__ float tanh_(float x) {
    // tanh(x) = 1 - 2/(exp(2x)+1); saturates correctly at +-inf
    return 1.0f - 2.0f * __builtin_amdgcn_rcpf(1.0f + __expf(2.0f * x));
}

// ---------------------------------------------------------------------------
// Generic MFMA GEMM: Y[M,Dout] = act( X1[M,K1] @ W1[Dout,K1]^T
//                                   (+ X2[M,K2] @ W2[Dout,K2]^T) (+b1) (+b2) )
// bf16 in, f32 accum. Output: bf16 to Y, or float32 to Yf if Yf != nullptr.
// One wave = 16 rows x Dout. NT = Dout/16 tiles.
// A-frag: lane holds A[m=l&15][k=quad*8+j]; B-frag: B[k][n=l&15] = W[n][k] rows.
// C: col=l&15 (j), row=quad*4+r.
// Requires: K1,K2 % 32 == 0, Dout % 16 == 0, M % 16 == 0, 16B-aligned bases.
// ---------------------------------------------------------------------------
template <int NT>
__global__ __launch_bounds__(256) void gemm_kernel(
    const u16* __restrict__ X1, const u16* __restrict__ W1, int K1,
    const u16* __restrict__ X2, const u16* __restrict__ W2, int K2,
    const u16* __restrict__ b1, const u16* __restrict__ b2,
    u16* __restrict__ Y, float* __restrict__ Yf,
    int M, int Dout, int do_relu)
{
    const int lane = threadIdx.x & 63;
    const int wave = threadIdx.x >> 6;
    const int row0 = (blockIdx.x * 4 + wave) * 16;
    if (row0 >= M) return;
    const int col  = lane & 15;
    const int quad = lane >> 4;

    f32x4 acc[NT];
#pragma unroll
    for (int jt = 0; jt < NT; ++jt) acc[jt] = (f32x4){0.f, 0.f, 0.f, 0.f};

    {
        const u16* xrow  = X1 + (size_t)(row0 + col) * K1 + quad * 8;
        const u16* wbase = W1 + (size_t)col * K1 + quad * 8;
        for (int kc = 0; kc < K1; kc += 32) {
            short8 a = *(const short8*)(xrow + kc);
#pragma unroll
            for (int jt = 0; jt < NT; ++jt) {
                short8 b = *(const short8*)(wbase + (size_t)jt * 16 * K1 + kc);
                acc[jt] = __builtin_amdgcn_mfma_f32_16x16x32_bf16(a, b, acc[jt], 0, 0, 0);
            }
        }
    }
    if (X2 != nullptr) {
        const u16* xrow  = X2 + (size_t)(row0 + col) * K2 + quad * 8;
        const u16* wbase = W2 + (size_t)col * K2 + quad * 8;
        for (int kc = 0; kc < K2; kc += 32) {
            short8 a = *(const short8*)(xrow + kc);
#pragma unroll
            for (int jt = 0; jt < NT; ++jt) {
                short8 b = *(const short8*)(wbase + (size_t)jt * 16 * K2 + kc);
                acc[jt] = __builtin_amdgcn_mfma_f32_16x16x32_bf16(a, b, acc[jt], 0, 0, 0);
            }
        }
    }

#pragma unroll
    for (int jt = 0; jt < NT; ++jt) {
        const int j = jt * 16 + col;
        float bias = 0.f;
        if (b1) bias += bf2f(b1[j]);
        if (b2) bias += bf2f(b2[j]);
#pragma unroll
        for (int r = 0; r < 4; ++r) {
            float v = acc[jt][r] + bias;
            if (do_relu) v = fmaxf(v, 0.f);
            size_t idx = (size_t)(row0 + quad * 4 + r) * Dout + j;
            if (Yf) Yf[idx] = v;
            else    Y[idx]  = f2bf(v);
        }
    }
}

// ---------------------------------------------------------------------------
// LSTM aggregation. Fixed dims: SEQ=16, hidden=64, gates=256.
// Per node n, step t: gates = G[src[n*16+t]] + Whh @ h   (bih+bhh folded in G)
//   i=[0,64) f=[64,128) g=[128,192) o=[192,256)
//   c = sig(f)*c + sig(i)*tanh(g);  h = sig(o)*tanh(c)
// One wave = 16 nodes. GEMM orientation: gates^T[256x16] = Whh[256x64] @ h^T.
//   A-frag = Whh rows (LDS, fragment-order, staged once per block)
//   B-frag = h^T (per-wave LDS buffer, fragment-order)
//   C: lane l -> node n = l&15, gate j = jt*16 + quad*4 + r  (4 consecutive j!)
// Acc init = 8B global load of G[s_n][j..j+3] per tile.
// ---------------------------------------------------------------------------
__global__ __launch_bounds__(256) void lstm_kernel(
    const u16* __restrict__ G,     // [N,256] bf16 (bih+bhh folded)
    const int* __restrict__ src,   // [N*16]
    const u16* __restrict__ whh,   // [256,64] bf16
    u16* __restrict__ Hout,        // [N,64] bf16
    int N)
{
    __shared__ u16 lds_whh[32 * 64 * 8];     // 32 frags x 64 lanes x 8 bf16 = 32KB
    __shared__ u16 lds_h[4][2 * 64 * 8];     // per wave: 2 frags x 64 lanes x 8 = 2KB
    __shared__ int lds_idx[4][16 * 16];      // per wave: [t][n]

    const int tid  = threadIdx.x;
    const int lane = tid & 63;
    const int wave = tid >> 6;
    const int col  = lane & 15;   // node within wave / W-row select
    const int quad = lane >> 4;

    // Stage Whh into LDS in fragment order: slot (f = jt*2+kc, l) holds
    // whh[jt*16 + (l&15)][kc*32 + (l>>4)*8 + 0..7]
    for (int s = tid; s < 32 * 64; s += 256) {
        int f = s >> 6, l = s & 63;
        int jt = f >> 1, kc = f & 1;
        int row = jt * 16 + (l & 15);
        int k0  = kc * 32 + (l >> 4) * 8;
        *(short8*)(lds_whh + (size_t)s * 8) = *(const short8*)(whh + row * 64 + k0);
    }

    const int node0 = (blockIdx.x * 4 + wave) * 16;
    const bool active = node0 < N;
    if (active) {
        // lane: node `col`, steps quad*4..quad*4+3
        const int* ip = src + (size_t)(node0 + col) * 16 + quad * 4;
        int4 v = *(const int4*)ip;
        lds_idx[wave][(quad * 4 + 0) * 16 + col] = v.x;
        lds_idx[wave][(quad * 4 + 1) * 16 + col] = v.y;
        lds_idx[wave][(quad * 4 + 2) * 16 + col] = v.z;
        lds_idx[wave][(quad * 4 + 3) * 16 + col] = v.w;
    }
    __syncthreads();
    if (!active) return;
    // After this point: waves are fully independent (own lds_h region, read-only
    // lds_whh/lds_idx) -> no further barriers needed.

    u16* myh = lds_h[wave];
    const int* myidx = lds_idx[wave];

    float c_[16];     // c[node=col][j = u*16 + quad*4 + r] at index u*4+r
#pragma unroll
    for (int i = 0; i < 16; ++i) c_[i] = 0.f;

    for (int t = 0; t < 16; ++t) {
        const int s = myidx[t * 16 + col];
        f32x4 acc[16];
        // init from G rows (4 consecutive gate values per 8B load)
        const u16* grow = G + (size_t)s * 256 + quad * 4;
#pragma unroll
        for (int jt = 0; jt < 16; ++jt) {
            uint2 g2 = *(const uint2*)(grow + jt * 16);
            f32x4 a;
            a[0] = bf2f((u16)(g2.x & 0xffffu));
            a[1] = bf2f((u16)(g2.x >> 16));
            a[2] = bf2f((u16)(g2.y & 0xffffu));
            a[3] = bf2f((u16)(g2.y >> 16));
            acc[jt] = a;
        }

        if (t > 0) {
            short8 hb0 = *(const short8*)(myh + (size_t)(0 * 64 + lane) * 8);
            short8 hb1 = *(const short8*)(myh + (size_t)(1 * 64 + lane) * 8);
#pragma unroll
            for (int jt = 0; jt < 16; ++jt) {
                short8 a0 = *(const short8*)(lds_whh + (size_t)((jt * 2 + 0) * 64 + lane) * 8);
                acc[jt] = __builtin_amdgcn_mfma_f32_16x16x32_bf16(a0, hb0, acc[jt], 0, 0, 0);
                short8 a1 = *(const short8*)(lds_whh + (size_t)((jt * 2 + 1) * 64 + lane) * 8);
                acc[jt] = __builtin_amdgcn_mfma_f32_16x16x32_bf16(a1, hb1, acc[jt], 0, 0, 0);
            }
        }

        // nonlinearity + state update; write h (bf16) for next step
#pragma unroll
        for (int u = 0; u < 4; ++u) {
            u16 hp[4];
#pragma unroll
            for (int r = 0; r < 4; ++r) {
                float iv = acc[u +  0][r];
                float fv = acc[u +  4][r];
                float gv = acc[u +  8][r];
                float ov = acc[u + 12][r];
                float cn = sigm(fv) * c_[u * 4 + r] + sigm(iv) * tanh_(gv);
                c_[u * 4 + r] = cn;
                float hv = sigm(ov) * tanh_(cn);
                hp[r] = f2bf(hv);
            }
            uint2 hw;
            hw.x = (u32)hp[0] | ((u32)hp[1] << 16);
            hw.y = (u32)hp[2] | ((u32)hp[3] << 16);
            if (t == 15) {
                // final: straight to global H[node][j], 8B per store
                *(uint2*)(Hout + (size_t)(node0 + col) * 64 + u * 16 + quad * 4) = hw;
            } else {
                // fragment-order LDS: element j' = u*16+quad*4+r of row col maps to
                // frag kc = u>>1, lane l' = quad'*16+col, quad' = (u&1)*2 + (quad>>1),
                // sub-offset (quad&1)*4 elements
                int kc = u >> 1;
                int quadp = ((u & 1) << 1) + (quad >> 1);
                u16* dst = myh + (size_t)((kc * 64 + quadp * 16 + col) * 8) + (quad & 1) * 4;
                *(uint2*)dst = hw;
            }
        }
    }
}

// ---------------------------------------------------------------------------
// edge_index (int32) -> float32 copy into tail of d_out
// ---------------------------------------------------------------------------
__global__ void edge_cast_kernel(const int* __restrict__ e, float* __restrict__ out, int n4)
{
    int i = blockIdx.x * blockDim.x + threadIdx.x;
    if (i < n4) {
        int4 v = *(const int4*)(e + (size_t)i * 4);
        float4 o;
        o.x = (float)v.x; o.y = (float)v.y; o.z = (float)v.z; o.w = (float)v.w;
        *(float4*)(out + (size_t)i * 4) = o;
    }
}

// ---------------------------------------------------------------------------
static void launch_gemm(const u16* X1, const u16* W1, int K1,
                        const u16* X2, const u16* W2, int K2,
                        const u16* b1, const u16* b2, u16* Y, float* Yf,
                        int M, int Dout, int relu, hipStream_t stream)
{
    dim3 grid((M + 63) / 64), block(256);
    switch (Dout / 16) {
    case 4:  hipLaunchKernelGGL((gemm_kernel<4>),  grid, block, 0, stream, X1, W1, K1, X2, W2, K2, b1, b2, Y, Yf, M, Dout, relu); break;
    case 8:  hipLaunchKernelGGL((gemm_kernel<8>),  grid, block, 0, stream, X1, W1, K1, X2, W2, K2, b1, b2, Y, Yf, M, Dout, relu); break;
    case 12: hipLaunchKernelGGL((gemm_kernel<12>), grid, block, 0, stream, X1, W1, K1, X2, W2, K2, b1, b2, Y, Yf, M, Dout, relu); break;
    case 16: hipLaunchKernelGGL((gemm_kernel<16>), grid, block, 0, stream, X1, W1, K1, X2, W2, K2, b1, b2, Y, Yf, M, Dout, relu); break;
    default: break;
    }
}

extern "C" void kernel_launch(void* const* d_in, const int* in_sizes, int n_in,
                              void* d_out, int out_size, void* d_ws, size_t ws_size,
                              hipStream_t stream)
{
    const u16* x       = (const u16*)d_in[0];
    const int* edge    = (const int*)d_in[1];   // [2,E]: row0=src, row1=dst
    // d_in[2] = max_deg (unused; structure is fixed-degree 16)
    const u16* p1_pw   = (const u16*)d_in[3];
    const u16* p1_pb   = (const u16*)d_in[4];
    const u16* p1_wih  = (const u16*)d_in[5];
    const u16* p1_whh  = (const u16*)d_in[6];
    const u16* p1_bih  = (const u16*)d_in[7];
    const u16* p1_bhh  = (const u16*)d_in[8];
    const u16* p1_llw  = (const u16*)d_in[9];
    const u16* p1_llb  = (const u16*)d_in[10];
    const u16* p1_lrw  = (const u16*)d_in[11];
    const u16* p2_pw   = (const u16*)d_in[12];
    const u16* p2_pb   = (const u16*)d_in[13];
    const u16* p2_wih  = (const u16*)d_in[14];
    const u16* p2_whh  = (const u16*)d_in[15];
    const u16* p2_bih  = (const u16*)d_in[16];
    const u16* p2_bhh  = (const u16*)d_in[17];
    const u16* p2_llw  = (const u16*)d_in[18];
    const u16* p2_llb  = (const u16*)d_in[19];
    const u16* p2_lrw  = (const u16*)d_in[20];
    const u16* lin1w   = (const u16*)d_in[21];
    const u16* lin1b   = (const u16*)d_in[22];
    const u16* lin2w   = (const u16*)d_in[23];
    const u16* lin2b   = (const u16*)d_in[24];
    const u16* lin3w   = (const u16*)d_in[25];
    const u16* lin3b   = (const u16*)d_in[26];
    (void)n_in; (void)ws_size;

    const int N  = in_sizes[0] / 64;     // 50000
    const int E2 = in_sizes[1];          // 2*E = 1600000
    const int* srcIdx = edge;            // edge_index[0]

    // workspace carve (bf16), peak 47MB; lifetimes disjoint where aliased:
    //   [ 0,26)MB : G (both layers); later Y2 [N,128] @0 (12.8MB), T1 [N,192] @13MB
    //   [26,33)MB : xp (both layers) — dead before T1 reaches 26MB
    //   [33,40)MB : H (lstm out) — dead before T2
    //   [40,47)MB : Y1 [N,64] (layer-2 root input)
    char* w = (char*)d_ws;
    u16* bufG  = (u16*)(w);
    u16* bufXP = (u16*)(w + 26u * 1024 * 1024);
    u16* bufH  = (u16*)(w + 33u * 1024 * 1024);
    u16* bufY1 = (u16*)(w + 40u * 1024 * 1024);
    u16* bufY2 = (u16*)(w);                         // reuses dead G region
    u16* bufT1 = (u16*)(w + 13u * 1024 * 1024);     // after Y2, into dead xp
    u16* bufT2 = (u16*)(w + 33u * 1024 * 1024);     // reuses dead H region

    float* out_h    = (float*)d_out;                 // [N,64] float32
    float* out_edge = (float*)d_out + (size_t)N * 64;// [2*E]  float32
    (void)out_size;

    // edge_index passthrough (int32 -> float32)
    {
        int n4 = E2 / 4;
        hipLaunchKernelGGL(edge_cast_kernel, dim3((n4 + 255) / 256), dim3(256), 0, stream,
                           edge, out_edge, n4);
    }

    dim3 lgrid((N + 63) / 64), lblock(256);

    // ---- SAGE layer 1 ----
    launch_gemm(x,     p1_pw,  64, nullptr, nullptr, 0, p1_pb, nullptr, bufXP, nullptr, N,  64, 1, stream); // xp1
    launch_gemm(bufXP, p1_wih, 64, nullptr, nullptr, 0, p1_bih, p1_bhh, bufG,  nullptr, N, 256, 0, stream); // G1 (+bih+bhh)
    hipLaunchKernelGGL(lstm_kernel, lgrid, lblock, 0, stream, bufG, srcIdx, p1_whh, bufH, N);               // H1
    launch_gemm(bufH,  p1_llw, 64, x,      p1_lrw, 64, p1_llb, nullptr, bufY1, nullptr, N,  64, 1, stream); // Y1

    // ---- SAGE layer 2 ----
    launch_gemm(bufY1, p2_pw,  64, nullptr, nullptr, 0, p2_pb, nullptr, bufXP, nullptr, N,  64, 1, stream); // xp2
    launch_gemm(bufXP, p2_wih, 64, nullptr, nullptr, 0, p2_bih, p2_bhh, bufG,  nullptr, N, 256, 0, stream); // G2
    hipLaunchKernelGGL(lstm_kernel, lgrid, lblock, 0, stream, bufG, srcIdx, p2_whh, bufH, N);               // H2
    launch_gemm(bufH,  p2_llw, 64, bufY1,  p2_lrw, 64, p2_llb, nullptr, bufY2, nullptr, N, 128, 1, stream); // Y2

    // ---- MLP head ----
    launch_gemm(bufY2, lin1w, 128, nullptr, nullptr, 0, lin1b, nullptr, bufT1, nullptr, N, 192, 1, stream); // T1
    launch_gemm(bufT1, lin2w, 192, nullptr, nullptr, 0, lin2b, nullptr, bufT2, nullptr, N,  64, 1, stream); // T2
    launch_gemm(bufT2, lin3w,  64, nullptr, nullptr, 0, lin3b, nullptr, nullptr, out_h, N,  64, 1, stream); // out (f32)
}

// Round 3
// 514.159 us; speedup vs baseline: 1.2729x; 1.2729x over previous
//
#include <hip/hip_runtime.h>
#include <hip/hip_bf16.h>

typedef unsigned short u16;
typedef unsigned int u32;
typedef __attribute__((ext_vector_type(8))) short short8;   // 8 bf16 (4 VGPRs) MFMA A/B frag
typedef __attribute__((ext_vector_type(4))) float f32x4;    // MFMA C/D frag

__device__ __forceinline__ float bf2f(u16 u) {
    union { u32 i; float f; } v; v.i = ((u32)u) << 16; return v.f;
}
__device__ __forceinline__ u16 f2bf(float f) {
    union { float f; u32 i; } v; v.f = f;
    u32 r = v.i + 0x7fffu + ((v.i >> 16) & 1u);   // RNE
    return (u16)(r >> 16);
}
__device__ __forceinline__ float sigm(float x) {
    return __builtin_amdgcn_rcpf(1.0f + __expf(-x));
}
__device__ __forceinline__ float tanh_(float x) {
    return 1.0f - 2.0f * __builtin_amdgcn_rcpf(1.0f + __expf(2.0f * x));
}
// within-wave LDS write->read fence (no block barrier; per-wave regions only)
__device__ __forceinline__ void lds_fence() {
    __asm__ __volatile__("s_waitcnt lgkmcnt(0)" ::: "memory");
}

// ---------------------------------------------------------------------------
// Generic MFMA GEMM (used for the dual ll/lr epilogue GEMMs):
// Y[M,Dout] = relu( X1[M,K1]@W1^T + X2[M,K2]@W2^T + b1 )
// ---------------------------------------------------------------------------
template <int NT>
__global__ __launch_bounds__(256) void gemm_kernel(
    const u16* __restrict__ X1, const u16* __restrict__ W1, int K1,
    const u16* __restrict__ X2, const u16* __restrict__ W2, int K2,
    const u16* __restrict__ b1,
    u16* __restrict__ Y, int M, int Dout)
{
    const int lane = threadIdx.x & 63;
    const int wave = threadIdx.x >> 6;
    const int row0 = (blockIdx.x * 4 + wave) * 16;
    if (row0 >= M) return;
    const int col  = lane & 15;
    const int quad = lane >> 4;

    f32x4 acc[NT];
#pragma unroll
    for (int jt = 0; jt < NT; ++jt) acc[jt] = (f32x4){0.f, 0.f, 0.f, 0.f};

    {
        const u16* xrow  = X1 + (size_t)(row0 + col) * K1 + quad * 8;
        const u16* wbase = W1 + (size_t)col * K1 + quad * 8;
        for (int kc = 0; kc < K1; kc += 32) {
            short8 a = *(const short8*)(xrow + kc);
#pragma unroll
            for (int jt = 0; jt < NT; ++jt) {
                short8 b = *(const short8*)(wbase + (size_t)jt * 16 * K1 + kc);
                acc[jt] = __builtin_amdgcn_mfma_f32_16x16x32_bf16(a, b, acc[jt], 0, 0, 0);
            }
        }
    }
    {
        const u16* xrow  = X2 + (size_t)(row0 + col) * K2 + quad * 8;
        const u16* wbase = W2 + (size_t)col * K2 + quad * 8;
        for (int kc = 0; kc < K2; kc += 32) {
            short8 a = *(const short8*)(xrow + kc);
#pragma unroll
            for (int jt = 0; jt < NT; ++jt) {
                short8 b = *(const short8*)(wbase + (size_t)jt * 16 * K2 + kc);
                acc[jt] = __builtin_amdgcn_mfma_f32_16x16x32_bf16(a, b, acc[jt], 0, 0, 0);
            }
        }
    }

#pragma unroll
    for (int jt = 0; jt < NT; ++jt) {
        const int j = jt * 16 + col;
        float bias = bf2f(b1[j]);
#pragma unroll
        for (int r = 0; r < 4; ++r) {
            float v = fmaxf(acc[jt][r] + bias, 0.f);
            Y[(size_t)(row0 + quad * 4 + r) * Dout + j] = f2bf(v);
        }
    }
}

// ---------------------------------------------------------------------------
// Fused projection + gate precompute:
//   xp = relu(X@pw^T + pb)            [16x64 per wave, via MFMA, C layout]
//   G  = xp@wih^T + bih + bhh         [16x256, lstm orientation -> 8B stores]
// Per-wave LDS transpose of xp (C layout -> B-frag layout), XOR-swizzled.
// ---------------------------------------------------------------------------
__global__ __launch_bounds__(256) void proj_gates_kernel(
    const u16* __restrict__ X,    // [M,64]
    const u16* __restrict__ pw,   // [64,64]
    const u16* __restrict__ pb,   // [64]
    const u16* __restrict__ wih,  // [256,64]
    const u16* __restrict__ bih, const u16* __restrict__ bhh, // [256]
    u16* __restrict__ G,          // [M,256]
    int M)
{
    __shared__ u16 xp_lds[4][16 * 64];   // 2KB per wave, swizzled 8-elt chunks

    const int lane = threadIdx.x & 63;
    const int wave = threadIdx.x >> 6;
    const int row0 = (blockIdx.x * 4 + wave) * 16;
    if (row0 >= M) return;
    const int col  = lane & 15;
    const int quad = lane >> 4;
    u16* xl = xp_lds[wave];

    // ---- GEMM1: xp, standard orientation (A = X rows, B = pw rows) ----
    f32x4 c1[4];
#pragma unroll
    for (int jt = 0; jt < 4; ++jt) c1[jt] = (f32x4){0.f, 0.f, 0.f, 0.f};
    {
        const u16* xrow = X  + (size_t)(row0 + col) * 64 + quad * 8;
        const u16* wrow = pw + (size_t)col * 64 + quad * 8;
#pragma unroll
        for (int kc = 0; kc < 64; kc += 32) {
            short8 a = *(const short8*)(xrow + kc);
#pragma unroll
            for (int jt = 0; jt < 4; ++jt) {
                short8 b = *(const short8*)(wrow + (size_t)jt * 16 * 64 + kc);
                c1[jt] = __builtin_amdgcn_mfma_f32_16x16x32_bf16(a, b, c1[jt], 0, 0, 0);
            }
        }
    }
    // epilogue: relu+bias; write LDS row-major [node][k], chunk-swizzled:
    // element (row,k) -> row*64 + ((k>>3 ^ (row&7))<<3) + (k&7)
#pragma unroll
    for (int jt = 0; jt < 4; ++jt) {
        float bias = bf2f(pb[jt * 16 + col]);
#pragma unroll
        for (int r = 0; r < 4; ++r) {
            float v = fmaxf(c1[jt][r] + bias, 0.f);
            int row = quad * 4 + r;
            int k   = jt * 16 + col;
            xl[row * 64 + ((((k >> 3) ^ (row & 7))) << 3) + (k & 7)] = f2bf(v);
        }
    }
    lds_fence();

    // ---- GEMM2: G^T = wih @ xp^T (lstm orientation) ----
    // B-frag: lane holds xp[node=col][kc*32 + quad*8 + 0..7]
    short8 b0, b1v;
    {
        int c0 = (0 * 4 + quad) ^ (col & 7);
        int c1i = (1 * 4 + quad) ^ (col & 7);
        b0  = *(const short8*)(xl + col * 64 + c0 * 8);
        b1v = *(const short8*)(xl + col * 64 + c1i * 8);
    }
#pragma unroll
    for (int jt = 0; jt < 16; ++jt) {
        // acc init = bih+bhh at j = jt*16 + quad*4 + (0..3)
        f32x4 acc;
        {
            uint2 u1 = *(const uint2*)(bih + jt * 16 + quad * 4);
            uint2 u2 = *(const uint2*)(bhh + jt * 16 + quad * 4);
            acc[0] = bf2f((u16)(u1.x & 0xffffu)) + bf2f((u16)(u2.x & 0xffffu));
            acc[1] = bf2f((u16)(u1.x >> 16))     + bf2f((u16)(u2.x >> 16));
            acc[2] = bf2f((u16)(u1.y & 0xffffu)) + bf2f((u16)(u2.y & 0xffffu));
            acc[3] = bf2f((u16)(u1.y >> 16))     + bf2f((u16)(u2.y >> 16));
        }
        const u16* arow = wih + (size_t)(jt * 16 + col) * 64 + quad * 8;
        short8 a0 = *(const short8*)(arow);
        acc = __builtin_amdgcn_mfma_f32_16x16x32_bf16(a0, b0, acc, 0, 0, 0);
        short8 a1 = *(const short8*)(arow + 32);
        acc = __builtin_amdgcn_mfma_f32_16x16x32_bf16(a1, b1v, acc, 0, 0, 0);
        // store 4 consecutive gates packed
        uint2 o;
        o.x = (u32)f2bf(acc[0]) | ((u32)f2bf(acc[1]) << 16);
        o.y = (u32)f2bf(acc[2]) | ((u32)f2bf(acc[3]) << 16);
        *(uint2*)(G + (size_t)(row0 + col) * 256 + jt * 16 + quad * 4) = o;
    }
}

// ---------------------------------------------------------------------------
// LSTM aggregation with G-gather software pipelining (prefetch t+1 during t).
// ---------------------------------------------------------------------------
__global__ __launch_bounds__(256) void lstm_kernel(
    const u16* __restrict__ G,     // [N,256] bf16 (bih+bhh folded)
    const int* __restrict__ src,   // [N*16]
    const u16* __restrict__ whh,   // [256,64] bf16
    u16* __restrict__ Hout,        // [N,64] bf16
    int N)
{
    __shared__ u16 lds_whh[32 * 64 * 8];     // 32KB
    __shared__ u16 lds_h[4][2 * 64 * 8];     // 2KB per wave
    __shared__ int lds_idx[4][16 * 16];      // per wave: [t][n]

    const int tid  = threadIdx.x;
    const int lane = tid & 63;
    const int wave = tid >> 6;
    const int col  = lane & 15;
    const int quad = lane >> 4;

    const int node0 = (blockIdx.x * 4 + wave) * 16;
    const bool active = node0 < N;

    // prefetch G for t=0 (overlaps whh staging + barrier)
    uint2 gbuf[16];
    {
        int s0 = active ? src[(size_t)(node0 + col) * 16] : 0;
        const u16* g0 = G + (size_t)s0 * 256 + quad * 4;
#pragma unroll
        for (int jt = 0; jt < 16; ++jt) gbuf[jt] = *(const uint2*)(g0 + jt * 16);
    }

    // Stage Whh into LDS in fragment order
    for (int s = tid; s < 32 * 64; s += 256) {
        int f = s >> 6, l = s & 63;
        int jt = f >> 1, kc = f & 1;
        int row = jt * 16 + (l & 15);
        int k0  = kc * 32 + (l >> 4) * 8;
        *(short8*)(lds_whh + (size_t)s * 8) = *(const short8*)(whh + row * 64 + k0);
    }
    if (active) {
        const int* ip = src + (size_t)(node0 + col) * 16 + quad * 4;
        int4 v = *(const int4*)ip;
        lds_idx[wave][(quad * 4 + 0) * 16 + col] = v.x;
        lds_idx[wave][(quad * 4 + 1) * 16 + col] = v.y;
        lds_idx[wave][(quad * 4 + 2) * 16 + col] = v.z;
        lds_idx[wave][(quad * 4 + 3) * 16 + col] = v.w;
    }
    __syncthreads();
    if (!active) return;
    // waves independent from here (own lds_h region; lds_whh/lds_idx read-only)

    u16* myh = lds_h[wave];
    const int* myidx = lds_idx[wave];

    float c_[16];
#pragma unroll
    for (int i = 0; i < 16; ++i) c_[i] = 0.f;

    for (int t = 0; t < 16; ++t) {
        // 1) convert current G regs into accumulators (frees gbuf regs)
        f32x4 acc[16];
#pragma unroll
        for (int jt = 0; jt < 16; ++jt) {
            uint2 g2 = gbuf[jt];
            f32x4 a;
            a[0] = bf2f((u16)(g2.x & 0xffffu));
            a[1] = bf2f((u16)(g2.x >> 16));
            a[2] = bf2f((u16)(g2.y & 0xffffu));
            a[3] = bf2f((u16)(g2.y >> 16));
            acc[jt] = a;
        }
        // 2) issue prefetch for t+1 (hidden behind MFMA + nonlinearity)
        if (t < 15) {
            int sn = myidx[(t + 1) * 16 + col];
            const u16* gn = G + (size_t)sn * 256 + quad * 4;
#pragma unroll
            for (int jt = 0; jt < 16; ++jt) gbuf[jt] = *(const uint2*)(gn + jt * 16);
        }
        // 3) recurrent GEMM
        if (t > 0) {
            short8 hb0 = *(const short8*)(myh + (size_t)(0 * 64 + lane) * 8);
            short8 hb1 = *(const short8*)(myh + (size_t)(1 * 64 + lane) * 8);
#pragma unroll
            for (int jt = 0; jt < 16; ++jt) {
                short8 a0 = *(const short8*)(lds_whh + (size_t)((jt * 2 + 0) * 64 + lane) * 8);
                acc[jt] = __builtin_amdgcn_mfma_f32_16x16x32_bf16(a0, hb0, acc[jt], 0, 0, 0);
                short8 a1 = *(const short8*)(lds_whh + (size_t)((jt * 2 + 1) * 64 + lane) * 8);
                acc[jt] = __builtin_amdgcn_mfma_f32_16x16x32_bf16(a1, hb1, acc[jt], 0, 0, 0);
            }
        }
        // 4) nonlinearity + state update
#pragma unroll
        for (int u = 0; u < 4; ++u) {
            u16 hp[4];
#pragma unroll
            for (int r = 0; r < 4; ++r) {
                float iv = acc[u +  0][r];
                float fv = acc[u +  4][r];
                float gv = acc[u +  8][r];
                float ov = acc[u + 12][r];
                float cn = sigm(fv) * c_[u * 4 + r] + sigm(iv) * tanh_(gv);
                c_[u * 4 + r] = cn;
                float hv = sigm(ov) * tanh_(cn);
                hp[r] = f2bf(hv);
            }
            uint2 hw;
            hw.x = (u32)hp[0] | ((u32)hp[1] << 16);
            hw.y = (u32)hp[2] | ((u32)hp[3] << 16);
            if (t == 15) {
                *(uint2*)(Hout + (size_t)(node0 + col) * 64 + u * 16 + quad * 4) = hw;
            } else {
                int kc = u >> 1;
                int quadp = ((u & 1) << 1) + (quad >> 1);
                u16* dst = myh + (size_t)((kc * 64 + quadp * 16 + col) * 8) + (quad & 1) * 4;
                *(uint2*)dst = hw;
            }
        }
    }
}

// ---------------------------------------------------------------------------
// Fused MLP head: out = relu(L3(relu(L2(relu(L1(X))))))  — f32 output
//   X [M,128] -> T1 [M,192] -> T2 [M,64] -> out [M,64]
// Per-wave LDS transposes (XOR-swizzled), weights straight from global (L1/L2 hot).
// ---------------------------------------------------------------------------
__global__ __launch_bounds__(256) void mlp_kernel(
    const u16* __restrict__ X,
    const u16* __restrict__ w1, const u16* __restrict__ b1,  // [192,128],[192]
    const u16* __restrict__ w2, const u16* __restrict__ b2,  // [64,192],[64]
    const u16* __restrict__ w3, const u16* __restrict__ b3,  // [64,64],[64]
    float* __restrict__ out, int M)
{
    __shared__ u16 t_lds[4][16 * 192];   // 6KB per wave (T1, then reused for T2)

    const int lane = threadIdx.x & 63;
    const int wave = threadIdx.x >> 6;
    const int row0 = (blockIdx.x * 4 + wave) * 16;
    if (row0 >= M) return;
    const int col  = lane & 15;
    const int quad = lane >> 4;
    u16* tl = t_lds[wave];

    // ---- GEMM1: T1 = relu(X@w1^T + b1), K=128, NT=12 ----
    f32x4 c1[12];
#pragma unroll
    for (int jt = 0; jt < 12; ++jt) c1[jt] = (f32x4){0.f, 0.f, 0.f, 0.f};
    {
        const u16* xrow = X  + (size_t)(row0 + col) * 128 + quad * 8;
        const u16* wrow = w1 + (size_t)col * 128 + quad * 8;
#pragma unroll
        for (int kc = 0; kc < 128; kc += 32) {
            short8 a = *(const short8*)(xrow + kc);
#pragma unroll
            for (int jt = 0; jt < 12; ++jt) {
                short8 b = *(const short8*)(wrow + (size_t)jt * 16 * 128 + kc);
                c1[jt] = __builtin_amdgcn_mfma_f32_16x16x32_bf16(a, b, c1[jt], 0, 0, 0);
            }
        }
    }
#pragma unroll
    for (int jt = 0; jt < 12; ++jt) {
        float bias = bf2f(b1[jt * 16 + col]);
#pragma unroll
        for (int r = 0; r < 4; ++r) {
            float v = fmaxf(c1[jt][r] + bias, 0.f);
            int row = jt? 0:0; row = quad * 4 + r;
            int k   = jt * 16 + col;
            tl[row * 192 + ((((k >> 3) ^ (row & 7))) << 3) + (k & 7)] = f2bf(v);
        }
    }
    lds_fence();

    // ---- GEMM2: T2 = relu(T1@w2^T + b2), K=192, NT=4 ----
    short8 af[6];
#pragma unroll
    for (int kc = 0; kc < 6; ++kc) {
        int ch = (kc * 4 + quad) ^ (col & 7);
        af[kc] = *(const short8*)(tl + col * 192 + ch * 8);
    }
    f32x4 c2[4];
#pragma unroll
    for (int jt = 0; jt < 4; ++jt) c2[jt] = (f32x4){0.f, 0.f, 0.f, 0.f};
#pragma unroll
    for (int kc = 0; kc < 6; ++kc) {
#pragma unroll
        for (int jt = 0; jt < 4; ++jt) {
            short8 b = *(const short8*)(w2 + (size_t)(jt * 16 + col) * 192 + kc * 32 + quad * 8);
            c2[jt] = __builtin_amdgcn_mfma_f32_16x16x32_bf16(af[kc], b, c2[jt], 0, 0, 0);
        }
    }
    // T2 -> LDS (row stride 64, swizzled); data-dep on all af reads, safe to overwrite
#pragma unroll
    for (int jt = 0; jt < 4; ++jt) {
        float bias = bf2f(b2[jt * 16 + col]);
#pragma unroll
        for (int r = 0; r < 4; ++r) {
            float v = fmaxf(c2[jt][r] + bias, 0.f);
            int row = quad * 4 + r;
            int k   = jt * 16 + col;
            tl[row * 64 + ((((k >> 3) ^ (row & 7))) << 3) + (k & 7)] = f2bf(v);
        }
    }
    lds_fence();

    // ---- GEMM3: out = relu(T2@w3^T + b3), K=64, NT=4, f32 store ----
    short8 ag[2];
#pragma unroll
    for (int kc = 0; kc < 2; ++kc) {
        int ch = (kc * 4 + quad) ^ (col & 7);
        ag[kc] = *(const short8*)(tl + col * 64 + ch * 8);
    }
    f32x4 c3[4];
#pragma unroll
    for (int jt = 0; jt < 4; ++jt) c3[jt] = (f32x4){0.f, 0.f, 0.f, 0.f};
#pragma unroll
    for (int kc = 0; kc < 2; ++kc) {
#pragma unroll
        for (int jt = 0; jt < 4; ++jt) {
            short8 b = *(const short8*)(w3 + (size_t)(jt * 16 + col) * 64 + kc * 32 + quad * 8);
            c3[jt] = __builtin_amdgcn_mfma_f32_16x16x32_bf16(ag[kc], b, c3[jt], 0, 0, 0);
        }
    }
#pragma unroll
    for (int jt = 0; jt < 4; ++jt) {
        float bias = bf2f(b3[jt * 16 + col]);
#pragma unroll
        for (int r = 0; r < 4; ++r) {
            float v = fmaxf(c3[jt][r] + bias, 0.f);
            out[(size_t)(row0 + quad * 4 + r) * 64 + jt * 16 + col] = v;
        }
    }
}

// ---------------------------------------------------------------------------
__global__ void edge_cast_kernel(const int* __restrict__ e, float* __restrict__ out, int n4)
{
    int i = blockIdx.x * blockDim.x + threadIdx.x;
    if (i < n4) {
        int4 v = *(const int4*)(e + (size_t)i * 4);
        float4 o;
        o.x = (float)v.x; o.y = (float)v.y; o.z = (float)v.z; o.w = (float)v.w;
        *(float4*)(out + (size_t)i * 4) = o;
    }
}

// ---------------------------------------------------------------------------
extern "C" void kernel_launch(void* const* d_in, const int* in_sizes, int n_in,
                              void* d_out, int out_size, void* d_ws, size_t ws_size,
                              hipStream_t stream)
{
    const u16* x       = (const u16*)d_in[0];
    const int* edge    = (const int*)d_in[1];
    const u16* p1_pw   = (const u16*)d_in[3];
    const u16* p1_pb   = (const u16*)d_in[4];
    const u16* p1_wih  = (const u16*)d_in[5];
    const u16* p1_whh  = (const u16*)d_in[6];
    const u16* p1_bih  = (const u16*)d_in[7];
    const u16* p1_bhh  = (const u16*)d_in[8];
    const u16* p1_llw  = (const u16*)d_in[9];
    const u16* p1_llb  = (const u16*)d_in[10];
    const u16* p1_lrw  = (const u16*)d_in[11];
    const u16* p2_pw   = (const u16*)d_in[12];
    const u16* p2_pb   = (const u16*)d_in[13];
    const u16* p2_wih  = (const u16*)d_in[14];
    const u16* p2_whh  = (const u16*)d_in[15];
    const u16* p2_bih  = (const u16*)d_in[16];
    const u16* p2_bhh  = (const u16*)d_in[17];
    const u16* p2_llw  = (const u16*)d_in[18];
    const u16* p2_llb  = (const u16*)d_in[19];
    const u16* p2_lrw  = (const u16*)d_in[20];
    const u16* lin1w   = (const u16*)d_in[21];
    const u16* lin1b   = (const u16*)d_in[22];
    const u16* lin2w   = (const u16*)d_in[23];
    const u16* lin2b   = (const u16*)d_in[24];
    const u16* lin3w   = (const u16*)d_in[25];
    const u16* lin3b   = (const u16*)d_in[26];
    (void)n_in; (void)ws_size;

    const int N  = in_sizes[0] / 64;     // 50000
    const int E2 = in_sizes[1];          // 1600000
    const int* srcIdx = edge;

    // workspace carve (peak 39.4MB):
    //   [ 0,26)MB : G (per layer); later Y2 [N,128] (G dead after its lstm)
    //   [26,33)MB : H (lstm out, per layer)
    //   [33,40)MB : Y1 [N,64]
    char* w = (char*)d_ws;
    u16* bufG  = (u16*)(w);
    u16* bufH  = (u16*)(w + 26u * 1024 * 1024);
    u16* bufY1 = (u16*)(w + 33u * 1024 * 1024);
    u16* bufY2 = (u16*)(w);

    float* out_h    = (float*)d_out;
    float* out_edge = (float*)d_out + (size_t)N * 64;
    (void)out_size;

    {
        int n4 = E2 / 4;
        hipLaunchKernelGGL(edge_cast_kernel, dim3((n4 + 255) / 256), dim3(256), 0, stream,
                           edge, out_edge, n4);
    }

    dim3 grid((N + 63) / 64), block(256);

    // ---- SAGE layer 1 ----
    hipLaunchKernelGGL(proj_gates_kernel, grid, block, 0, stream,
                       x, p1_pw, p1_pb, p1_wih, p1_bih, p1_bhh, bufG, N);
    hipLaunchKernelGGL(lstm_kernel, grid, block, 0, stream, bufG, srcIdx, p1_whh, bufH, N);
    hipLaunchKernelGGL((gemm_kernel<4>), grid, block, 0, stream,
                       bufH, p1_llw, 64, x, p1_lrw, 64, p1_llb, bufY1, N, 64);

    // ---- SAGE layer 2 ----
    hipLaunchKernelGGL(proj_gates_kernel, grid, block, 0, stream,
                       bufY1, p2_pw, p2_pb, p2_wih, p2_bih, p2_bhh, bufG, N);
    hipLaunchKernelGGL(lstm_kernel, grid, block, 0, stream, bufG, srcIdx, p2_whh, bufH, N);
    hipLaunchKernelGGL((gemm_kernel<8>), grid, block, 0, stream,
                       bufH, p2_llw, 64, bufY1, p2_lrw, 64, p2_llb, bufY2, N, 128);

    // ---- MLP head (fused lin1+lin2+lin3) ----
    hipLaunchKernelGGL(mlp_kernel, grid, block, 0, stream,
                       bufY2, lin1w, lin1b, lin2w, lin2b, lin3w, lin3b, out_h, N);
}